// Round 15
// baseline (20613.808 us; speedup 1.0000x reference)
//
#include <hip/hip_runtime.h>
#include <hip/hip_bf16.h>

// LSTM layer: T=512, B=64, I=1024, H=1024, fp32.
// R15: R10-R14 showed barrier mechanics irrelevant; invariant ~13us/step ==
// h-broadcast cost: 256 blocks x 256KB bypass-atomic reads = 64MB/step =
// 4.2M 8B transactions at the L3 coherence point (~300GT/s -> ~13.7us).
// Fix: 64 blocks x 1024 threads (4 waves/SIMD TLP). Block owns 16 units
// (64 gate rows); 16 waves = 4 gates x 4 batch-tiles, full-K tiles (no
// split-K). h staged ONCE per block per k-quarter into XOR-swizzled LDS
// via proven 8B agent atomics -> 16MB/step, 1M transactions. W_hh via
// normal cached loads (read-only, L2-hot). Publish/barrier/gx unchanged.

#define BH 65536  // B*H floats

typedef __attribute__((ext_vector_type(8))) short bf16x8;  // 8 bf16 (4 VGPRs)
typedef __attribute__((ext_vector_type(4))) float f32x4;
typedef unsigned long long ull;

__device__ inline ushort f2bf(float x) {
    __hip_bfloat16 b = __float2bfloat16(x);
    return *(ushort*)&b;
}
__device__ inline float bf2f(ushort u) {
    __hip_bfloat16 b = *(__hip_bfloat16*)&u;
    return __bfloat162float(b);
}

// ---------------- fp32 -> (hi,lo) bf16 planes (grid-stride) -----------------
__global__ void split_bf16(const float* __restrict__ src,
                           ushort* __restrict__ hi, ushort* __restrict__ lo,
                           long n)
{
    long i0 = ((long)blockIdx.x * blockDim.x + threadIdx.x) * 4;
    long stride = (long)gridDim.x * blockDim.x * 4;
    for (long e = i0; e < n; e += stride) {
        float4 v = *(const float4*)(src + e);
        ushort4 hv, lv;
        hv.x = f2bf(v.x); lv.x = f2bf(v.x - bf2f(hv.x));
        hv.y = f2bf(v.y); lv.y = f2bf(v.y - bf2f(hv.y));
        hv.z = f2bf(v.z); lv.z = f2bf(v.z - bf2f(hv.z));
        hv.w = f2bf(v.w); lv.w = f2bf(v.w - bf2f(hv.w));
        *(ushort4*)(hi + e) = hv;
        *(ushort4*)(lo + e) = lv;
    }
}

// ---------------- bf16x3 MFMA gx GEMM: gx = x·Wih^T + bias, permuted --------
__global__ __launch_bounds__(256)
void gx_mfma(const ushort* __restrict__ xhi, const ushort* __restrict__ xlo,
             const ushort* __restrict__ whi, const ushort* __restrict__ wlo,
             const float* __restrict__ bih, const float* __restrict__ bhh,
             float* __restrict__ gxp)
{
    __shared__ short lds[4][4096];      // planes Ahi,Alo,Bhi,Blo: [128][32] bf16
    const int tid  = threadIdx.x;
    const int lane = tid & 63;
    const int w    = tid >> 6;          // wave 0..3
    const int wm   = w >> 1, wn = w & 1;
    const int mt0  = blockIdx.y * 128;  // chunk-local m = trel*64 + b
    const int nt0  = blockIdx.x * 128;  // gate row r

    const int lr_ = w * 16 + (lane >> 2);
    const int lc_ = (lane & 3) * 8;

    f32x4 acc[4][4] = {};

    for (int kt = 0; kt < 1024; kt += 32) {
        uint4 rah[2], ral[2], rbh[2], rbl[2];
        #pragma unroll
        for (int s = 0; s < 2; ++s) {
            size_t ao = (size_t)(mt0 + s * 64 + lr_) * 1024 + kt + lc_;
            size_t bo = (size_t)(nt0 + s * 64 + lr_) * 1024 + kt + lc_;
            rah[s] = *(const uint4*)(xhi + ao);
            ral[s] = *(const uint4*)(xlo + ao);
            rbh[s] = *(const uint4*)(whi + bo);
            rbl[s] = *(const uint4*)(wlo + bo);
        }
        __syncthreads();
        #pragma unroll
        for (int s = 0; s < 2; ++s) {
            int row = s * 64 + lr_;
            int us  = (lane & 3) ^ ((row >> 1) & 3);
            int off = row * 32 + us * 8;               // shorts
            *(uint4*)&lds[0][off] = rah[s];
            *(uint4*)&lds[1][off] = ral[s];
            *(uint4*)&lds[2][off] = rbh[s];
            *(uint4*)&lds[3][off] = rbl[s];
        }
        __syncthreads();
        bf16x8 ah[4], al[4], bh[4], bl[4];
        #pragma unroll
        for (int f = 0; f < 4; ++f) {
            int arow = wm * 64 + f * 16 + (lane & 15);
            int brow = wn * 64 + f * 16 + (lane & 15);
            int aus  = (lane >> 4) ^ ((arow >> 1) & 3);
            int bus  = (lane >> 4) ^ ((brow >> 1) & 3);
            int ar = arow * 32 + aus * 8;
            int br = brow * 32 + bus * 8;
            ah[f] = *(bf16x8*)&lds[0][ar];
            al[f] = *(bf16x8*)&lds[1][ar];
            bh[f] = *(bf16x8*)&lds[2][br];
            bl[f] = *(bf16x8*)&lds[3][br];
        }
        #pragma unroll
        for (int i = 0; i < 4; ++i)
            #pragma unroll
            for (int j = 0; j < 4; ++j) {
                acc[i][j] = __builtin_amdgcn_mfma_f32_16x16x32_bf16(ah[i], bh[j], acc[i][j], 0, 0, 0);
                acc[i][j] = __builtin_amdgcn_mfma_f32_16x16x32_bf16(ah[i], bl[j], acc[i][j], 0, 0, 0);
                acc[i][j] = __builtin_amdgcn_mfma_f32_16x16x32_bf16(al[i], bh[j], acc[i][j], 0, 0, 0);
            }
    }
    #pragma unroll
    for (int j = 0; j < 4; ++j) {
        int r = nt0 + wn * 64 + j * 16 + (lane & 15);
        float bias = bih[r] + bhh[r];
        int g = r >> 10, u = r & 1023;
        #pragma unroll
        for (int i = 0; i < 4; ++i) {
            #pragma unroll
            for (int e = 0; e < 4; ++e) {
                int m = mt0 + wm * 64 + i * 16 + (lane >> 4) * 4 + e;
                int trel = m >> 6, b = m & 63;
                gxp[(((size_t)trel * 256 + (u >> 2)) * 64 + b) * 16 + g * 4 + (u & 3)]
                    = acc[i][j][e] + bias;
            }
        }
    }
}

// ----------------------- fp32 gx GEMM (small-ws fallback) -------------------
#define BM 128
#define BN 128
#define BKg 16

__global__ __launch_bounds__(256, 2)
void gx_gemm(const float* __restrict__ x, const float* __restrict__ Wih,
             const float* __restrict__ bih, const float* __restrict__ bhh,
             float* __restrict__ gxp, int t0)
{
    __shared__ float As[BKg][BM + 4];
    __shared__ float Bs[BKg][BN + 4];
    const int tid  = threadIdx.x;
    const int nblk = blockIdx.x;
    const int mblk = blockIdx.y;
    const int lrow = tid >> 2;
    const int lkq  = (tid & 3) * 4;
    const int ty   = tid >> 4;
    const int tx   = tid & 15;

    const float* xb = x   + ((size_t)t0 * 64 + (size_t)mblk * BM) * 1024;
    const float* wb = Wih + (size_t)nblk * BN * 1024;

    float acc[8][8] = {};
    for (int kt = 0; kt < 1024; kt += BKg) {
        const int k0 = kt + lkq;
        float4 a0 = *(const float4*)(xb + (size_t)lrow        * 1024 + k0);
        float4 a1 = *(const float4*)(xb + (size_t)(lrow + 64) * 1024 + k0);
        float4 b0 = *(const float4*)(wb + (size_t)lrow        * 1024 + k0);
        float4 b1 = *(const float4*)(wb + (size_t)(lrow + 64) * 1024 + k0);
        __syncthreads();
        As[lkq + 0][lrow] = a0.x; As[lkq + 1][lrow] = a0.y;
        As[lkq + 2][lrow] = a0.z; As[lkq + 3][lrow] = a0.w;
        As[lkq + 0][lrow + 64] = a1.x; As[lkq + 1][lrow + 64] = a1.y;
        As[lkq + 2][lrow + 64] = a1.z; As[lkq + 3][lrow + 64] = a1.w;
        Bs[lkq + 0][lrow] = b0.x; Bs[lkq + 1][lrow] = b0.y;
        Bs[lkq + 2][lrow] = b0.z; Bs[lkq + 3][lrow] = b0.w;
        Bs[lkq + 0][lrow + 64] = b1.x; Bs[lkq + 1][lrow + 64] = b1.y;
        Bs[lkq + 2][lrow + 64] = b1.z; Bs[lkq + 3][lrow + 64] = b1.w;
        __syncthreads();
        #pragma unroll
        for (int kk = 0; kk < BKg; ++kk) {
            float4 af0 = *(float4*)&As[kk][ty * 8];
            float4 af1 = *(float4*)&As[kk][ty * 8 + 4];
            float4 bf0 = *(float4*)&Bs[kk][tx * 8];
            float4 bf1 = *(float4*)&Bs[kk][tx * 8 + 4];
            float a[8] = {af0.x, af0.y, af0.z, af0.w, af1.x, af1.y, af1.z, af1.w};
            float b[8] = {bf0.x, bf0.y, bf0.z, bf0.w, bf1.x, bf1.y, bf1.z, bf1.w};
            #pragma unroll
            for (int i = 0; i < 8; ++i)
                #pragma unroll
                for (int j = 0; j < 8; ++j)
                    acc[i][j] += a[i] * b[j];
        }
    }
    float bias[8];
    #pragma unroll
    for (int j = 0; j < 8; ++j) {
        int r = nblk * BN + tx * 8 + j;
        bias[j] = bih[r] + bhh[r];
    }
    #pragma unroll
    for (int i = 0; i < 8; ++i) {
        int ml   = mblk * BM + ty * 8 + i;
        int trel = ml >> 6, b = ml & 63;
        #pragma unroll
        for (int jj = 0; jj < 2; ++jj) {
            int r = nblk * BN + tx * 8 + jj * 4;
            int g = r >> 10, u = r & 1023;
            float4 v = make_float4(acc[i][jj*4+0] + bias[jj*4+0],
                                   acc[i][jj*4+1] + bias[jj*4+1],
                                   acc[i][jj*4+2] + bias[jj*4+2],
                                   acc[i][jj*4+3] + bias[jj*4+3]);
            *(float4*)(gxp + ((((size_t)trel * 256 + (u >> 2)) * 64 + b) << 4) + g * 4) = v;
        }
    }
}

// ---------- de-contended fence-free barrier (64 blocks) ---------------------
__device__ inline void flagbar64(uint token, uint* flags, uint* gen)
{
    __syncthreads();                    // drains vmcnt -> h stores at L3
    const int tid = threadIdx.x;
    if (blockIdx.x == 0) {
        if (tid == 0)
            __hip_atomic_store(&flags[0], token, __ATOMIC_RELAXED, __HIP_MEMORY_SCOPE_AGENT);
        if (tid < 64) {
            while (__hip_atomic_load(&flags[tid * 16], __ATOMIC_RELAXED, __HIP_MEMORY_SCOPE_AGENT) < token)
                __builtin_amdgcn_s_sleep(2);
        }
        __syncthreads();                // all 64 flags seen
        if (tid < 32)
            __hip_atomic_store(&gen[tid * 16], token, __ATOMIC_RELAXED, __HIP_MEMORY_SCOPE_AGENT);
    } else {
        if (tid == 0) {
            __hip_atomic_store(&flags[blockIdx.x * 16], token, __ATOMIC_RELAXED, __HIP_MEMORY_SCOPE_AGENT);
            uint* myg = &gen[(blockIdx.x & 31) * 16];
            while (__hip_atomic_load(myg, __ATOMIC_RELAXED, __HIP_MEMORY_SCOPE_AGENT) < token)
                __builtin_amdgcn_s_sleep(2);
        }
    }
    __syncthreads();
}

// -------- persistent recurrence: 64 blocks x 1024 threads -------------------
// Block cu owns units cu*16..cu*16+15 (64 gate rows r_local = g*16+ul).
// 16 waves = gate g (wid>>2) x batch-tile wc (wid&3); each computes a 16x16
// output tile over all K. h staged per k-quarter in swizzled LDS (8B agent
// atomics, one copy per block). W_hh via normal cached loads (L2-hot).
__global__ __launch_bounds__(1024, 4)
void lstm_persist(const ushort* __restrict__ whh_hi, const ushort* __restrict__ whh_lo,
                  const float* __restrict__ gxp, ushort* __restrict__ hpl,
                  const float* __restrict__ c0, float* __restrict__ cbuf,
                  float* __restrict__ out, int t0, int chunk, uint* bar)
{
    __shared__ uint4  hstage[2][2048];  // [plane][batch*32 + phys_u16] 64KB
    __shared__ float  pre[64][65];      // gate-row x batch gather (16.6KB)
    __shared__ ushort hstg2[64][32];    // publish stage: hi[16] lo[16] (4KB)

    const int tid  = threadIdx.x;
    const int lane = tid & 63;
    const int wid  = tid >> 6;          // 0..15
    const int g    = wid >> 2;          // gate 0..3
    const int wc   = wid & 3;           // batch tile 0..3
    const int cu   = blockIdx.x;        // unit block (16 units)
    uint* flags = bar;
    uint* gen   = bar + 4096;

    const int ul_a  = lane & 15;        // A row = unit within gate tile
    const int kl    = (lane >> 4) * 8;  // k offset within 32-k step
    const int batch = wc * 16 + (lane & 15);   // B col = batch
    const ushort* wbase_hi = whh_hi + (size_t)(g * 1024 + cu * 16 + ul_a) * 1024;
    const ushort* wbase_lo = whh_lo + (size_t)(g * 1024 + cu * 16 + ul_a) * 1024;

    // elementwise mapping: one (unit, batch) per thread
    const int ul = tid & 15, b = tid >> 4;
    const int hcol = cu * 16 + ul;
    float c_reg = (t0 == 0) ? c0[b * 1024 + hcol] : cbuf[b * 1024 + hcol];

    // staging mapping: thread covers batch sb, u16 pair su..su+1 (64B total)
    const int sb = tid >> 4;
    const int su = (tid & 15) * 2;

    for (int t = t0; t < t0 + chunk; ++t) {
        const ushort* hin_hi = hpl + (size_t)(((t + 1) & 1) * 2 + 0) * BH;
        const ushort* hin_lo = hpl + (size_t)(((t + 1) & 1) * 2 + 1) * BH;

        // hoist gx (HBM, h-independent)
        const float* gx = gxp + (((size_t)(t - t0) * 256 + cu * 4 + (ul >> 2)) * 64 + b) * 16;
        int ul2 = ul & 3;
        float gxv0 = gx[0 + ul2], gxv1 = gx[4 + ul2];
        float gxv2 = gx[8 + ul2], gxv3 = gx[12 + ul2];

        f32x4 acc = {};
        ull rh[4], rl[4];
        // issue stage(q=0)
        {
            const ull* shi = (const ull*)(hin_hi + sb * 1024 + su * 8);
            const ull* slo = (const ull*)(hin_lo + sb * 1024 + su * 8);
            #pragma unroll
            for (int i = 0; i < 4; ++i) {
                rh[i] = __hip_atomic_load(shi + i, __ATOMIC_RELAXED, __HIP_MEMORY_SCOPE_AGENT);
                rl[i] = __hip_atomic_load(slo + i, __ATOMIC_RELAXED, __HIP_MEMORY_SCOPE_AGENT);
            }
        }
        for (int q = 0; q < 4; ++q) {
            __syncthreads();            // prev-q reads done; stage data arrived
                                        // (syncthreads drains vmcnt+lgkmcnt)
            {
                ull* hs0 = (ull*)&hstage[0][0];
                ull* hs1 = (ull*)&hstage[1][0];
                int u0 = (su)     ^ (sb & 7);
                int u1 = (su + 1) ^ (sb & 7);
                hs0[sb * 64 + u0 * 2 + 0] = rh[0];
                hs0[sb * 64 + u0 * 2 + 1] = rh[1];
                hs0[sb * 64 + u1 * 2 + 0] = rh[2];
                hs0[sb * 64 + u1 * 2 + 1] = rh[3];
                hs1[sb * 64 + u0 * 2 + 0] = rl[0];
                hs1[sb * 64 + u0 * 2 + 1] = rl[1];
                hs1[sb * 64 + u1 * 2 + 0] = rl[2];
                hs1[sb * 64 + u1 * 2 + 1] = rl[3];
            }
            __syncthreads();
            if (q < 3) {                // prefetch next quarter under compute
                const ull* shi = (const ull*)(hin_hi + sb * 1024 + (q + 1) * 256 + su * 8);
                const ull* slo = (const ull*)(hin_lo + sb * 1024 + (q + 1) * 256 + su * 8);
                #pragma unroll
                for (int i = 0; i < 4; ++i) {
                    rh[i] = __hip_atomic_load(shi + i, __ATOMIC_RELAXED, __HIP_MEMORY_SCOPE_AGENT);
                    rl[i] = __hip_atomic_load(slo + i, __ATOMIC_RELAXED, __HIP_MEMORY_SCOPE_AGENT);
                }
            }
            #pragma unroll
            for (int ks = 0; ks < 8; ++ks) {
                // A (W_hh) cached from L2
                const ushort* wp = wbase_hi + q * 256 + ks * 32 + kl;
                bf16x8 a_hi = *(const bf16x8*)wp;
                bf16x8 a_lo = *(const bf16x8*)(wbase_lo + q * 256 + ks * 32 + kl);
                // B (h) from swizzled LDS
                int u16  = ks * 4 + (lane >> 4);
                int phys = u16 ^ (batch & 7);
                bf16x8 b_hi = *(bf16x8*)&hstage[0][batch * 32 + phys];
                bf16x8 b_lo = *(bf16x8*)&hstage[1][batch * 32 + phys];
                acc = __builtin_amdgcn_mfma_f32_16x16x32_bf16(a_hi, b_hi, acc, 0, 0, 0);
                acc = __builtin_amdgcn_mfma_f32_16x16x32_bf16(a_hi, b_lo, acc, 0, 0, 0);
                acc = __builtin_amdgcn_mfma_f32_16x16x32_bf16(a_lo, b_hi, acc, 0, 0, 0);
            }
        }
        // gather gates: D row=(lane>>4)*4+e -> unit, col=lane&15 -> batch
        #pragma unroll
        for (int e = 0; e < 4; ++e)
            pre[g * 16 + (lane >> 4) * 4 + e][wc * 16 + (lane & 15)] = acc[e];
        __syncthreads();

        float p0 = pre[ 0 + ul][b] + gxv0;
        float p1 = pre[16 + ul][b] + gxv1;
        float p2 = pre[32 + ul][b] + gxv2;
        float p3 = pre[48 + ul][b] + gxv3;
        float gi = __fdividef(1.0f, 1.0f + __expf(-p0));
        float gf = __fdividef(1.0f, 1.0f + __expf(-p1));
        float gg = 1.0f - __fdividef(2.0f, __expf(2.0f * p2) + 1.0f);
        float go = __fdividef(1.0f, 1.0f + __expf(-p3));
        c_reg = gf * c_reg + gi * gg;
        float hn = go * (1.0f - __fdividef(2.0f, __expf(2.0f * c_reg) + 1.0f));

        out[((size_t)t * 64 + b) * 1024 + hcol] = hn;
        ushort hh = f2bf(hn);
        hstg2[b][ul]      = hh;
        hstg2[b][16 + ul] = f2bf(hn - bf2f(hh));
        if (t == 511) {
            out[(size_t)512 * BH + b * 1024 + hcol]      = hn;     // h_fin
            out[(size_t)512 * BH + BH + b * 1024 + hcol] = c_reg;  // c_fin
        }
        __syncthreads();                // hstg2 complete
        // publish: thread t: batch=t>>4, word j=t&15 (j<8 hi, j>=8 lo)
        {
            int pb = tid >> 4, j = tid & 15;
            const uint* row = (const uint*)&hstg2[pb][0];
            ushort* ho = hpl + (size_t)((t & 1) * 2) * BH + pb * 1024 + cu * 16;
            if (j < 8)
                __hip_atomic_store((uint*)ho + j, row[j],
                                   __ATOMIC_RELAXED, __HIP_MEMORY_SCOPE_AGENT);
            else
                __hip_atomic_store((uint*)(ho + BH) + (j - 8), row[j],
                                   __ATOMIC_RELAXED, __HIP_MEMORY_SCOPE_AGENT);
        }
        flagbar64((uint)(t + 1), flags, gen);
    }
    if (t0 + chunk < 512)
        cbuf[b * 1024 + hcol] = c_reg;
}

// ---------------- per-step fallback (R6-proven, 256 blocks) ------------------
__global__ __launch_bounds__(256)
void lstm_step_mfma(const ushort* __restrict__ whh_hi, const ushort* __restrict__ whh_lo,
                    const float* __restrict__ gxp,
                    const ushort* __restrict__ hin_hi, const ushort* __restrict__ hin_lo,
                    const float* __restrict__ cprev, float* __restrict__ cbuf,
                    ushort* __restrict__ hout_hi, ushort* __restrict__ hout_lo,
                    float* __restrict__ out, int t, int trel)
{
    __shared__ float part[4][64][20];
    const int tid  = threadIdx.x;
    const int lane = tid & 63;
    const int w    = tid >> 6;
    const int cu   = blockIdx.x;

    const int rl    = lane & 15;
    const size_t wrow = (size_t)((rl >> 2) * 1024 + cu * 4 + (rl & 3)) * 1024;
    const int klane = (lane >> 4) * 8;
    const int kbase = w * 256;
    const int bq    = lane & 15;

    f32x4 acc[4] = {};
    #pragma unroll
    for (int ks = 0; ks < 8; ++ks) {
        int k0 = kbase + ks * 32 + klane;
        bf16x8 a_hi = *(const bf16x8*)(whh_hi + wrow + k0);
        bf16x8 a_lo = *(const bf16x8*)(whh_lo + wrow + k0);
        #pragma unroll
        for (int nt = 0; nt < 4; ++nt) {
            size_t ho = (size_t)(nt * 16 + bq) * 1024 + k0;
            bf16x8 b_hi = *(const bf16x8*)(hin_hi + ho);
            bf16x8 b_lo = *(const bf16x8*)(hin_lo + ho);
            acc[nt] = __builtin_amdgcn_mfma_f32_16x16x32_bf16(a_hi, b_hi, acc[nt], 0, 0, 0);
            acc[nt] = __builtin_amdgcn_mfma_f32_16x16x32_bf16(a_hi, b_lo, acc[nt], 0, 0, 0);
            acc[nt] = __builtin_amdgcn_mfma_f32_16x16x32_bf16(a_lo, b_hi, acc[nt], 0, 0, 0);
        }
    }
    const int r0 = (lane >> 4) * 4;
    #pragma unroll
    for (int nt = 0; nt < 4; ++nt)
        *(f32x4*)&part[w][nt * 16 + bq][r0] = acc[nt];
    __syncthreads();

    const int eb = tid >> 2, eu = tid & 3;
    const float* gx = gxp + (((size_t)trel * 256 + cu) * 64 + eb) * 16;
    float pre[4];
    #pragma unroll
    for (int g = 0; g < 4; ++g) {
        int r = g * 4 + eu;
        pre[g] = part[0][eb][r] + part[1][eb][r] + part[2][eb][r] + part[3][eb][r]
               + gx[g * 4 + eu];
    }
    float gi = __fdividef(1.0f, 1.0f + __expf(-pre[0]));
    float gf = __fdividef(1.0f, 1.0f + __expf(-pre[1]));
    float gg = 1.0f - __fdividef(2.0f, __expf(2.0f * pre[2]) + 1.0f);
    float go = __fdividef(1.0f, 1.0f + __expf(-pre[3]));
    float c_reg = cprev[eb * 1024 + cu * 4 + eu];
    c_reg = gf * c_reg + gi * gg;
    float hn = go * (1.0f - __fdividef(2.0f, __expf(2.0f * c_reg) + 1.0f));

    int hcol = cu * 4 + eu;
    cbuf[eb * 1024 + hcol] = c_reg;
    out[((size_t)t * 64 + eb) * 1024 + hcol] = hn;
    ushort hh = f2bf(hn);
    hout_hi[eb * 1024 + hcol] = hh;
    hout_lo[eb * 1024 + hcol] = f2bf(hn - bf2f(hh));
    if (t == 511) {
        out[(size_t)512 * BH + eb * 1024 + hcol]      = hn;
        out[(size_t)512 * BH + BH + eb * 1024 + hcol] = c_reg;
    }
}

// --------------------------------- host -------------------------------------
extern "C" void kernel_launch(void* const* d_in, const int* in_sizes, int n_in,
                              void* d_out, int out_size, void* d_ws, size_t ws_size,
                              hipStream_t stream)
{
    const float* x   = (const float*)d_in[0];
    const float* h0  = (const float*)d_in[1];
    const float* c0  = (const float*)d_in[2];
    const float* Wih = (const float*)d_in[3];
    const float* Whh = (const float*)d_in[4];
    const float* bih = (const float*)d_in[5];
    const float* bhh = (const float*)d_in[6];
    float* out = (float*)d_out;

    char* ws = (char*)d_ws;
    float* cbuf = (float*)ws;                            // 256 KB

    // layout: [cbuf 256K][wih_hi 8M][wih_lo 8M][whh_hi 8M][whh_lo 8M][hpl 512K]
    //         [bar 32K][xhi Tc*128K][xlo Tc*128K][gxp Tc*1M]
    const size_t FIXED0 = 262144 + 4 * 8388608L + 524288;   // up to bar
    const size_t FIXED  = FIXED0 + 32768;
    const long   PER    = 2 * 131072L + 1048576L;
    long Tc = ((long)ws_size - (long)FIXED) / PER;

    if (Tc >= 2) {
        if (Tc > 512) Tc = 512;
        Tc &= ~1L;
        ushort* wih_hi = (ushort*)(ws + 262144);
        ushort* wih_lo = wih_hi + 4194304;
        ushort* whh_hi = wih_lo + 4194304;
        ushort* whh_lo = whh_hi + 4194304;
        ushort* hpl    = whh_lo + 4194304;   // [buf 2][plane 2][BH] ushorts
        uint*   bar    = (uint*)(ws + FIXED0);
        char*   var    = ws + FIXED;
        ushort* xhi    = (ushort*)var;
        ushort* xlo    = (ushort*)(var + Tc * 131072);
        float*  gxp    = (float*)(var + Tc * 262144);

        hipMemsetAsync(bar, 0, 32768, stream);   // flags + gen replicas = 0
        split_bf16<<<dim3(2048), dim3(256), 0, stream>>>(Wih, wih_hi, wih_lo, 4194304L);
        split_bf16<<<dim3(2048), dim3(256), 0, stream>>>(Whh, whh_hi, whh_lo, 4194304L);
        split_bf16<<<dim3(64),   dim3(256), 0, stream>>>(h0, hpl + 2 * BH, hpl + 3 * BH, (long)BH);

        bool coop_ok = true;
        for (int t0 = 0; t0 < 512; t0 += (int)Tc) {
            int chunk = (512 - t0 < (int)Tc) ? (512 - t0) : (int)Tc;
            split_bf16<<<dim3(4096), dim3(256), 0, stream>>>(
                x + (size_t)t0 * BH, xhi, xlo, (long)chunk * BH);
            gx_mfma<<<dim3(32, chunk / 2), dim3(256), 0, stream>>>(
                xhi, xlo, wih_hi, wih_lo, bih, bhh, gxp);
            if (coop_ok) {
                void* args[] = {(void*)&whh_hi, (void*)&whh_lo, (void*)&gxp,
                                (void*)&hpl, (void*)&c0, (void*)&cbuf,
                                (void*)&out, (void*)&t0, (void*)&chunk,
                                (void*)&bar};
                hipError_t e = hipLaunchCooperativeKernel(
                    (void*)lstm_persist, dim3(64), dim3(1024), args, 0, stream);
                if (e != hipSuccess) { (void)hipGetLastError(); coop_ok = false; }
            }
            if (!coop_ok) {
                for (int trel = 0; trel < chunk; ++trel) {
                    int t = t0 + trel;
                    int rb = (t + 1) & 1, wb = t & 1;
                    const float* cp = (t == 0) ? c0 : cbuf;
                    lstm_step_mfma<<<dim3(256), dim3(256), 0, stream>>>(
                        whh_hi, whh_lo, gxp,
                        hpl + rb * 2 * BH, hpl + rb * 2 * BH + BH,
                        cp, cbuf,
                        hpl + wb * 2 * BH, hpl + wb * 2 * BH + BH,
                        out, t, trel);
                }
            }
        }
    } else {
        // small-ws fallback: fp32 gx GEMM + per-step MFMA recurrence
        ushort* whh_hi = (ushort*)(ws + 262144);
        ushort* whh_lo = whh_hi + 4194304;
        ushort* hpl    = whh_lo + 4194304;
        const size_t FIXED2 = 262144 + 2 * 8388608L + 524288;
        float* gxp = (float*)(ws + FIXED2);
        long Tc2 = ((long)ws_size - (long)FIXED2) / 1048576L;
        if (Tc2 > 512) Tc2 = 512;
        Tc2 &= ~1L;
        if (Tc2 < 2) Tc2 = 2;

        split_bf16<<<dim3(2048), dim3(256), 0, stream>>>(Whh, whh_hi, whh_lo, 4194304L);
        split_bf16<<<dim3(64),   dim3(256), 0, stream>>>(h0, hpl + 2 * BH, hpl + 3 * BH, (long)BH);

        for (int t0 = 0; t0 < 512; t0 += (int)Tc2) {
            int chunk = (512 - t0 < (int)Tc2) ? (512 - t0) : (int)Tc2;
            gx_gemm<<<dim3(32, chunk * 64 / BM), dim3(256), 0, stream>>>(
                x, Wih, bih, bhh, gxp, t0);
            for (int trel = 0; trel < chunk; ++trel) {
                int t = t0 + trel;
                int rb = (t + 1) & 1, wb = t & 1;
                const float* cp = (t == 0) ? c0 : cbuf;
                lstm_step_mfma<<<dim3(256), dim3(256), 0, stream>>>(
                    whh_hi, whh_lo, gxp,
                    hpl + rb * 2 * BH, hpl + rb * 2 * BH + BH,
                    cp, cbuf,
                    hpl + wb * 2 * BH, hpl + wb * 2 * BH + BH,
                    out, t, trel);
            }
        }
    }
}

// Round 16
// 11317.591 us; speedup vs baseline: 1.8214x; 1.8214x over previous
//
#include <hip/hip_runtime.h>
#include <hip/hip_bf16.h>

// LSTM layer: T=512, B=64, I=1024, H=1024, fp32.
// R16: R15 falsified the traffic theory (4x less h traffic -> 2x slower;
// W left registers = 16MB/step L2 misses). Revert to R14 structure. Real
// bottleneck: 1 wave/SIMD => ~32 dependent bypass-load latency exposures
// (~700cy each) per step = ~9.5us exposed, nothing to hide it. Fix = TLP:
// 256 blocks x 1024 threads (16 waves = kq x nt, 4 waves/SIMD). Same
// register-resident W per wave, same part[4][64][20], each wave 1/4 the
// loads. Elementwise on tid<256, publish tid<128. Barrier/publish/gx
// pipeline byte-identical to R14 (bench-validated).

#define BH 65536  // B*H floats

typedef __attribute__((ext_vector_type(8))) short bf16x8;  // 8 bf16 (4 VGPRs)
typedef __attribute__((ext_vector_type(4))) float f32x4;
typedef unsigned long long ull;

__device__ inline ushort f2bf(float x) {
    __hip_bfloat16 b = __float2bfloat16(x);
    return *(ushort*)&b;
}
__device__ inline float bf2f(ushort u) {
    __hip_bfloat16 b = *(__hip_bfloat16*)&u;
    return __bfloat162float(b);
}

// agent-coherent 16B load of h (2x8B relaxed atomic, L2-bypass, always fresh)
__device__ inline bf16x8 ldh16(const ushort* p) {
    union { ull q[2]; bf16x8 v; } u;
    u.q[0] = __hip_atomic_load((const ull*)p,
                               __ATOMIC_RELAXED, __HIP_MEMORY_SCOPE_AGENT);
    u.q[1] = __hip_atomic_load((const ull*)(p + 4),
                               __ATOMIC_RELAXED, __HIP_MEMORY_SCOPE_AGENT);
    return u.v;
}

// ---------------- fp32 -> (hi,lo) bf16 planes (grid-stride) -----------------
__global__ void split_bf16(const float* __restrict__ src,
                           ushort* __restrict__ hi, ushort* __restrict__ lo,
                           long n)
{
    long i0 = ((long)blockIdx.x * blockDim.x + threadIdx.x) * 4;
    long stride = (long)gridDim.x * blockDim.x * 4;
    for (long e = i0; e < n; e += stride) {
        float4 v = *(const float4*)(src + e);
        ushort4 hv, lv;
        hv.x = f2bf(v.x); lv.x = f2bf(v.x - bf2f(hv.x));
        hv.y = f2bf(v.y); lv.y = f2bf(v.y - bf2f(hv.y));
        hv.z = f2bf(v.z); lv.z = f2bf(v.z - bf2f(hv.z));
        hv.w = f2bf(v.w); lv.w = f2bf(v.w - bf2f(hv.w));
        *(ushort4*)(hi + e) = hv;
        *(ushort4*)(lo + e) = lv;
    }
}

// ---------------- bf16x3 MFMA gx GEMM: gx = x·Wih^T + bias, permuted --------
__global__ __launch_bounds__(256)
void gx_mfma(const ushort* __restrict__ xhi, const ushort* __restrict__ xlo,
             const ushort* __restrict__ whi, const ushort* __restrict__ wlo,
             const float* __restrict__ bih, const float* __restrict__ bhh,
             float* __restrict__ gxp)
{
    __shared__ short lds[4][4096];      // planes Ahi,Alo,Bhi,Blo: [128][32] bf16
    const int tid  = threadIdx.x;
    const int lane = tid & 63;
    const int w    = tid >> 6;          // wave 0..3
    const int wm   = w >> 1, wn = w & 1;
    const int mt0  = blockIdx.y * 128;  // chunk-local m = trel*64 + b
    const int nt0  = blockIdx.x * 128;  // gate row r

    const int lr_ = w * 16 + (lane >> 2);
    const int lc_ = (lane & 3) * 8;

    f32x4 acc[4][4] = {};

    for (int kt = 0; kt < 1024; kt += 32) {
        uint4 rah[2], ral[2], rbh[2], rbl[2];
        #pragma unroll
        for (int s = 0; s < 2; ++s) {
            size_t ao = (size_t)(mt0 + s * 64 + lr_) * 1024 + kt + lc_;
            size_t bo = (size_t)(nt0 + s * 64 + lr_) * 1024 + kt + lc_;
            rah[s] = *(const uint4*)(xhi + ao);
            ral[s] = *(const uint4*)(xlo + ao);
            rbh[s] = *(const uint4*)(whi + bo);
            rbl[s] = *(const uint4*)(wlo + bo);
        }
        __syncthreads();
        #pragma unroll
        for (int s = 0; s < 2; ++s) {
            int row = s * 64 + lr_;
            int us  = (lane & 3) ^ ((row >> 1) & 3);
            int off = row * 32 + us * 8;               // shorts
            *(uint4*)&lds[0][off] = rah[s];
            *(uint4*)&lds[1][off] = ral[s];
            *(uint4*)&lds[2][off] = rbh[s];
            *(uint4*)&lds[3][off] = rbl[s];
        }
        __syncthreads();
        bf16x8 ah[4], al[4], bh[4], bl[4];
        #pragma unroll
        for (int f = 0; f < 4; ++f) {
            int arow = wm * 64 + f * 16 + (lane & 15);
            int brow = wn * 64 + f * 16 + (lane & 15);
            int aus  = (lane >> 4) ^ ((arow >> 1) & 3);
            int bus  = (lane >> 4) ^ ((brow >> 1) & 3);
            int ar = arow * 32 + aus * 8;
            int br = brow * 32 + bus * 8;
            ah[f] = *(bf16x8*)&lds[0][ar];
            al[f] = *(bf16x8*)&lds[1][ar];
            bh[f] = *(bf16x8*)&lds[2][br];
            bl[f] = *(bf16x8*)&lds[3][br];
        }
        #pragma unroll
        for (int i = 0; i < 4; ++i)
            #pragma unroll
            for (int j = 0; j < 4; ++j) {
                acc[i][j] = __builtin_amdgcn_mfma_f32_16x16x32_bf16(ah[i], bh[j], acc[i][j], 0, 0, 0);
                acc[i][j] = __builtin_amdgcn_mfma_f32_16x16x32_bf16(ah[i], bl[j], acc[i][j], 0, 0, 0);
                acc[i][j] = __builtin_amdgcn_mfma_f32_16x16x32_bf16(al[i], bh[j], acc[i][j], 0, 0, 0);
            }
    }
    #pragma unroll
    for (int j = 0; j < 4; ++j) {
        int r = nt0 + wn * 64 + j * 16 + (lane & 15);
        float bias = bih[r] + bhh[r];
        int g = r >> 10, u = r & 1023;
        #pragma unroll
        for (int i = 0; i < 4; ++i) {
            #pragma unroll
            for (int e = 0; e < 4; ++e) {
                int m = mt0 + wm * 64 + i * 16 + (lane >> 4) * 4 + e;
                int trel = m >> 6, b = m & 63;
                gxp[(((size_t)trel * 256 + (u >> 2)) * 64 + b) * 16 + g * 4 + (u & 3)]
                    = acc[i][j][e] + bias;
            }
        }
    }
}

// ----------------------- fp32 gx GEMM (small-ws fallback) -------------------
#define BM 128
#define BN 128
#define BKg 16

__global__ __launch_bounds__(256, 2)
void gx_gemm(const float* __restrict__ x, const float* __restrict__ Wih,
             const float* __restrict__ bih, const float* __restrict__ bhh,
             float* __restrict__ gxp, int t0)
{
    __shared__ float As[BKg][BM + 4];
    __shared__ float Bs[BKg][BN + 4];
    const int tid  = threadIdx.x;
    const int nblk = blockIdx.x;
    const int mblk = blockIdx.y;
    const int lrow = tid >> 2;
    const int lkq  = (tid & 3) * 4;
    const int ty   = tid >> 4;
    const int tx   = tid & 15;

    const float* xb = x   + ((size_t)t0 * 64 + (size_t)mblk * BM) * 1024;
    const float* wb = Wih + (size_t)nblk * BN * 1024;

    float acc[8][8] = {};
    for (int kt = 0; kt < 1024; kt += BKg) {
        const int k0 = kt + lkq;
        float4 a0 = *(const float4*)(xb + (size_t)lrow        * 1024 + k0);
        float4 a1 = *(const float4*)(xb + (size_t)(lrow + 64) * 1024 + k0);
        float4 b0 = *(const float4*)(wb + (size_t)lrow        * 1024 + k0);
        float4 b1 = *(const float4*)(wb + (size_t)(lrow + 64) * 1024 + k0);
        __syncthreads();
        As[lkq + 0][lrow] = a0.x; As[lkq + 1][lrow] = a0.y;
        As[lkq + 2][lrow] = a0.z; As[lkq + 3][lrow] = a0.w;
        As[lkq + 0][lrow + 64] = a1.x; As[lkq + 1][lrow + 64] = a1.y;
        As[lkq + 2][lrow + 64] = a1.z; As[lkq + 3][lrow + 64] = a1.w;
        Bs[lkq + 0][lrow] = b0.x; Bs[lkq + 1][lrow] = b0.y;
        Bs[lkq + 2][lrow] = b0.z; Bs[lkq + 3][lrow] = b0.w;
        Bs[lkq + 0][lrow + 64] = b1.x; Bs[lkq + 1][lrow + 64] = b1.y;
        Bs[lkq + 2][lrow + 64] = b1.z; Bs[lkq + 3][lrow + 64] = b1.w;
        __syncthreads();
        #pragma unroll
        for (int kk = 0; kk < BKg; ++kk) {
            float4 af0 = *(float4*)&As[kk][ty * 8];
            float4 af1 = *(float4*)&As[kk][ty * 8 + 4];
            float4 bf0 = *(float4*)&Bs[kk][tx * 8];
            float4 bf1 = *(float4*)&Bs[kk][tx * 8 + 4];
            float a[8] = {af0.x, af0.y, af0.z, af0.w, af1.x, af1.y, af1.z, af1.w};
            float b[8] = {bf0.x, bf0.y, bf0.z, bf0.w, bf1.x, bf1.y, bf1.z, bf1.w};
            #pragma unroll
            for (int i = 0; i < 8; ++i)
                #pragma unroll
                for (int j = 0; j < 8; ++j)
                    acc[i][j] += a[i] * b[j];
        }
    }
    float bias[8];
    #pragma unroll
    for (int j = 0; j < 8; ++j) {
        int r = nblk * BN + tx * 8 + j;
        bias[j] = bih[r] + bhh[r];
    }
    #pragma unroll
    for (int i = 0; i < 8; ++i) {
        int ml   = mblk * BM + ty * 8 + i;
        int trel = ml >> 6, b = ml & 63;
        #pragma unroll
        for (int jj = 0; jj < 2; ++jj) {
            int r = nblk * BN + tx * 8 + jj * 4;
            int g = r >> 10, u = r & 1023;
            float4 v = make_float4(acc[i][jj*4+0] + bias[jj*4+0],
                                   acc[i][jj*4+1] + bias[jj*4+1],
                                   acc[i][jj*4+2] + bias[jj*4+2],
                                   acc[i][jj*4+3] + bias[jj*4+3]);
            *(float4*)(gxp + ((((size_t)trel * 256 + (u >> 2)) * 64 + b) << 4) + g * 4) = v;
        }
    }
}

// ---------- de-contended fence-free barrier (256 blocks, 1024 threads) ------
// flags: 1 uint per 64B line; gen: 32 replicas on separate lines.
__device__ inline void flagbar(uint token, uint* flags, uint* gen)
{
    __syncthreads();                    // drains vmcnt -> h stores at L3
    const int tid = threadIdx.x;
    if (blockIdx.x == 0) {
        if (tid == 0)
            __hip_atomic_store(&flags[0], token, __ATOMIC_RELAXED, __HIP_MEMORY_SCOPE_AGENT);
        if (tid < 256) {
            while (__hip_atomic_load(&flags[tid * 16], __ATOMIC_RELAXED, __HIP_MEMORY_SCOPE_AGENT) < token)
                __builtin_amdgcn_s_sleep(2);
        }
        __syncthreads();                // all 256 flags seen
        if (tid < 32)
            __hip_atomic_store(&gen[tid * 16], token, __ATOMIC_RELAXED, __HIP_MEMORY_SCOPE_AGENT);
    } else {
        if (tid == 0) {
            __hip_atomic_store(&flags[blockIdx.x * 16], token, __ATOMIC_RELAXED, __HIP_MEMORY_SCOPE_AGENT);
            uint* myg = &gen[(blockIdx.x & 31) * 16];
            while (__hip_atomic_load(myg, __ATOMIC_RELAXED, __HIP_MEMORY_SCOPE_AGENT) < token)
                __builtin_amdgcn_s_sleep(2);
        }
    }
    __syncthreads();
}

// -------- persistent recurrence: 256 blocks x 1024 threads (4 waves/SIMD) ---
// Block cu owns units cu*4..cu*4+3 (16 gate-rows). Wave (kq = wid>>2,
// nt = wid&3): partial over kq's 256 K for batch group nt. W slice in regs.
__global__ __launch_bounds__(1024, 4)
void lstm_persist(const ushort* __restrict__ whh_hi, const ushort* __restrict__ whh_lo,
                  const float* __restrict__ gxp, ushort* __restrict__ hpl,
                  const float* __restrict__ c0, float* __restrict__ cbuf,
                  float* __restrict__ out, int t0, int chunk, uint* bar)
{
    __shared__ float  part[4][64][20];  // [kq][b][r + pad4] = 20KB
    __shared__ ushort hstg[64][8];      // h stage: cols 0..3 hi, 4..7 lo (1KB)
    const int tid  = threadIdx.x;
    const int lane = tid & 63;
    const int wid  = tid >> 6;          // 0..15
    const int kq   = wid >> 2;          // k-quarter
    const int nt   = wid & 3;           // batch group
    const int cu   = blockIdx.x;
    uint* flags = bar;                  // 256 lines (16KB)
    uint* gen   = bar + 4096;           // 32 lines, at byte 16K

    const int rl    = lane & 15;        // A row = local gate-row
    const size_t wrow = (size_t)((rl >> 2) * 1024 + cu * 4 + (rl & 3)) * 1024;
    const int klane = (lane >> 4) * 8;
    const int kbase = kq * 256;
    const int bq    = lane & 15;        // B col = batch within 16-group

    bf16x8 a_hi[8], a_lo[8];            // W kq-slice resident in registers
    #pragma unroll
    for (int ks = 0; ks < 8; ++ks) {
        int k0 = kbase + ks * 32 + klane;
        a_hi[ks] = *(const bf16x8*)(whh_hi + wrow + k0);
        a_lo[ks] = *(const bf16x8*)(whh_lo + wrow + k0);
    }

    const int eb = (tid >> 2) & 63, eu = tid & 3;    // valid for tid<256
    const int hcol = cu * 4 + eu;
    float c_reg = 0.0f;
    if (tid < 256)
        c_reg = (t0 == 0) ? c0[eb * 1024 + hcol] : cbuf[eb * 1024 + hcol];

    for (int t = t0; t < t0 + chunk; ++t) {
        const ushort* hin_hi = hpl + (size_t)(((t + 1) & 1) * 2 + 0) * BH;
        const ushort* hin_lo = hpl + (size_t)(((t + 1) & 1) * 2 + 1) * BH;

        // hoist gx read (HBM, h-independent) off the critical path
        float gxv0 = 0, gxv1 = 0, gxv2 = 0, gxv3 = 0;
        if (tid < 256) {
            const float* gx = gxp + (((size_t)(t - t0) * 256 + cu) * 64 + eb) * 16;
            gxv0 = gx[0 + eu]; gxv1 = gx[4 + eu];
            gxv2 = gx[8 + eu]; gxv3 = gx[12 + eu];
        }

        f32x4 acc = {};
        #pragma unroll
        for (int ks = 0; ks < 8; ++ks) {
            int k0 = kbase + ks * 32 + klane;
            size_t ho = (size_t)(nt * 16 + bq) * 1024 + k0;
            bf16x8 b_hi = ldh16(hin_hi + ho);
            bf16x8 b_lo = ldh16(hin_lo + ho);
            acc = __builtin_amdgcn_mfma_f32_16x16x32_bf16(a_hi[ks], b_hi, acc, 0, 0, 0);
            acc = __builtin_amdgcn_mfma_f32_16x16x32_bf16(a_hi[ks], b_lo, acc, 0, 0, 0);
            acc = __builtin_amdgcn_mfma_f32_16x16x32_bf16(a_lo[ks], b_hi, acc, 0, 0, 0);
        }
        const int r0 = (lane >> 4) * 4;
        *(f32x4*)&part[kq][nt * 16 + bq][r0] = acc;
        __syncthreads();

        if (tid < 256) {
            float pre0 = part[0][eb][0  + eu] + part[1][eb][0  + eu] + part[2][eb][0  + eu] + part[3][eb][0  + eu] + gxv0;
            float pre1 = part[0][eb][4  + eu] + part[1][eb][4  + eu] + part[2][eb][4  + eu] + part[3][eb][4  + eu] + gxv1;
            float pre2 = part[0][eb][8  + eu] + part[1][eb][8  + eu] + part[2][eb][8  + eu] + part[3][eb][8  + eu] + gxv2;
            float pre3 = part[0][eb][12 + eu] + part[1][eb][12 + eu] + part[2][eb][12 + eu] + part[3][eb][12 + eu] + gxv3;
            float gi = __fdividef(1.0f, 1.0f + __expf(-pre0));
            float gf = __fdividef(1.0f, 1.0f + __expf(-pre1));
            float gg = 1.0f - __fdividef(2.0f, __expf(2.0f * pre2) + 1.0f);
            float go = __fdividef(1.0f, 1.0f + __expf(-pre3));
            c_reg = gf * c_reg + gi * gg;
            float hn = go * (1.0f - __fdividef(2.0f, __expf(2.0f * c_reg) + 1.0f));

            out[((size_t)t * 64 + eb) * 1024 + hcol] = hn;
            ushort hh = f2bf(hn);
            hstg[eb][eu]     = hh;
            hstg[eb][4 + eu] = f2bf(hn - bf2f(hh));
            if (t == 511) {
                out[(size_t)512 * BH + eb * 1024 + hcol]      = hn;     // h_fin
                out[(size_t)512 * BH + BH + eb * 1024 + hcol] = c_reg;  // c_fin
            }
        }
        __syncthreads();                // hstg complete
        // publish h: 128 threads store uint pairs, agent-scope (write-through)
        if (tid < 128) {
            int eb2 = tid >> 1, jj = tid & 1;
            const uint* row = (const uint*)&hstg[eb2][0];
            ushort* hobase = hpl + (size_t)((t & 1) * 2) * BH + eb2 * 1024 + cu * 4;
            __hip_atomic_store((uint*)hobase + jj,      row[jj],
                               __ATOMIC_RELAXED, __HIP_MEMORY_SCOPE_AGENT);
            __hip_atomic_store((uint*)(hobase + BH) + jj, row[2 + jj],
                               __ATOMIC_RELAXED, __HIP_MEMORY_SCOPE_AGENT);
        }
        flagbar((uint)(t + 1), flags, gen);   // entry syncthreads drains vmcnt
    }
    if (t0 + chunk < 512 && tid < 256)
        cbuf[eb * 1024 + hcol] = c_reg;
}

// ---------------- per-step fallback (R6-proven, 256 blocks x 256) ------------
__global__ __launch_bounds__(256)
void lstm_step_mfma(const ushort* __restrict__ whh_hi, const ushort* __restrict__ whh_lo,
                    const float* __restrict__ gxp,
                    const ushort* __restrict__ hin_hi, const ushort* __restrict__ hin_lo,
                    const float* __restrict__ cprev, float* __restrict__ cbuf,
                    ushort* __restrict__ hout_hi, ushort* __restrict__ hout_lo,
                    float* __restrict__ out, int t, int trel)
{
    __shared__ float part[4][64][20];
    const int tid  = threadIdx.x;
    const int lane = tid & 63;
    const int w    = tid >> 6;
    const int cu   = blockIdx.x;

    const int rl    = lane & 15;
    const size_t wrow = (size_t)((rl >> 2) * 1024 + cu * 4 + (rl & 3)) * 1024;
    const int klane = (lane >> 4) * 8;
    const int kbase = w * 256;
    const int bq    = lane & 15;

    f32x4 acc[4] = {};
    #pragma unroll
    for (int ks = 0; ks < 8; ++ks) {
        int k0 = kbase + ks * 32 + klane;
        bf16x8 a_hi = *(const bf16x8*)(whh_hi + wrow + k0);
        bf16x8 a_lo = *(const bf16x8*)(whh_lo + wrow + k0);
        #pragma unroll
        for (int nt = 0; nt < 4; ++nt) {
            size_t ho = (size_t)(nt * 16 + bq) * 1024 + k0;
            bf16x8 b_hi = *(const bf16x8*)(hin_hi + ho);
            bf16x8 b_lo = *(const bf16x8*)(hin_lo + ho);
            acc[nt] = __builtin_amdgcn_mfma_f32_16x16x32_bf16(a_hi, b_hi, acc[nt], 0, 0, 0);
            acc[nt] = __builtin_amdgcn_mfma_f32_16x16x32_bf16(a_hi, b_lo, acc[nt], 0, 0, 0);
            acc[nt] = __builtin_amdgcn_mfma_f32_16x16x32_bf16(a_lo, b_hi, acc[nt], 0, 0, 0);
        }
    }
    const int r0 = (lane >> 4) * 4;
    #pragma unroll
    for (int nt = 0; nt < 4; ++nt)
        *(f32x4*)&part[w][nt * 16 + bq][r0] = acc[nt];
    __syncthreads();

    const int eb = tid >> 2, eu = tid & 3;
    const float* gx = gxp + (((size_t)trel * 256 + cu) * 64 + eb) * 16;
    float pre[4];
    #pragma unroll
    for (int g = 0; g < 4; ++g) {
        int r = g * 4 + eu;
        pre[g] = part[0][eb][r] + part[1][eb][r] + part[2][eb][r] + part[3][eb][r]
               + gx[g * 4 + eu];
    }
    float gi = __fdividef(1.0f, 1.0f + __expf(-pre[0]));
    float gf = __fdividef(1.0f, 1.0f + __expf(-pre[1]));
    float gg = 1.0f - __fdividef(2.0f, __expf(2.0f * pre[2]) + 1.0f);
    float go = __fdividef(1.0f, 1.0f + __expf(-pre[3]));
    float c_reg = cprev[eb * 1024 + cu * 4 + eu];
    c_reg = gf * c_reg + gi * gg;
    float hn = go * (1.0f - __fdividef(2.0f, __expf(2.0f * c_reg) + 1.0f));

    int hcol = cu * 4 + eu;
    cbuf[eb * 1024 + hcol] = c_reg;
    out[((size_t)t * 64 + eb) * 1024 + hcol] = hn;
    ushort hh = f2bf(hn);
    hout_hi[eb * 1024 + hcol] = hh;
    hout_lo[eb * 1024 + hcol] = f2bf(hn - bf2f(hh));
    if (t == 511) {
        out[(size_t)512 * BH + eb * 1024 + hcol]      = hn;
        out[(size_t)512 * BH + BH + eb * 1024 + hcol] = c_reg;
    }
}

// --------------------------------- host -------------------------------------
extern "C" void kernel_launch(void* const* d_in, const int* in_sizes, int n_in,
                              void* d_out, int out_size, void* d_ws, size_t ws_size,
                              hipStream_t stream)
{
    const float* x   = (const float*)d_in[0];
    const float* h0  = (const float*)d_in[1];
    const float* c0  = (const float*)d_in[2];
    const float* Wih = (const float*)d_in[3];
    const float* Whh = (const float*)d_in[4];
    const float* bih = (const float*)d_in[5];
    const float* bhh = (const float*)d_in[6];
    float* out = (float*)d_out;

    char* ws = (char*)d_ws;
    float* cbuf = (float*)ws;                            // 256 KB

    // layout: [cbuf 256K][wih_hi 8M][wih_lo 8M][whh_hi 8M][whh_lo 8M][hpl 512K]
    //         [bar 32K][xhi Tc*128K][xlo Tc*128K][gxp Tc*1M]
    const size_t FIXED0 = 262144 + 4 * 8388608L + 524288;   // up to bar
    const size_t FIXED  = FIXED0 + 32768;
    const long   PER    = 2 * 131072L + 1048576L;
    long Tc = ((long)ws_size - (long)FIXED) / PER;

    if (Tc >= 2) {
        if (Tc > 512) Tc = 512;
        Tc &= ~1L;
        ushort* wih_hi = (ushort*)(ws + 262144);
        ushort* wih_lo = wih_hi + 4194304;
        ushort* whh_hi = wih_lo + 4194304;
        ushort* whh_lo = whh_hi + 4194304;
        ushort* hpl    = whh_lo + 4194304;   // [buf 2][plane 2][BH] ushorts
        uint*   bar    = (uint*)(ws + FIXED0);
        char*   var    = ws + FIXED;
        ushort* xhi    = (ushort*)var;
        ushort* xlo    = (ushort*)(var + Tc * 131072);
        float*  gxp    = (float*)(var + Tc * 262144);

        hipMemsetAsync(bar, 0, 32768, stream);   // flags + gen replicas = 0
        split_bf16<<<dim3(2048), dim3(256), 0, stream>>>(Wih, wih_hi, wih_lo, 4194304L);
        split_bf16<<<dim3(2048), dim3(256), 0, stream>>>(Whh, whh_hi, whh_lo, 4194304L);
        split_bf16<<<dim3(64),   dim3(256), 0, stream>>>(h0, hpl + 2 * BH, hpl + 3 * BH, (long)BH);

        bool coop_ok = true;
        for (int t0 = 0; t0 < 512; t0 += (int)Tc) {
            int chunk = (512 - t0 < (int)Tc) ? (512 - t0) : (int)Tc;
            split_bf16<<<dim3(4096), dim3(256), 0, stream>>>(
                x + (size_t)t0 * BH, xhi, xlo, (long)chunk * BH);
            gx_mfma<<<dim3(32, chunk / 2), dim3(256), 0, stream>>>(
                xhi, xlo, wih_hi, wih_lo, bih, bhh, gxp);
            if (coop_ok) {
                void* args[] = {(void*)&whh_hi, (void*)&whh_lo, (void*)&gxp,
                                (void*)&hpl, (void*)&c0, (void*)&cbuf,
                                (void*)&out, (void*)&t0, (void*)&chunk,
                                (void*)&bar};
                hipError_t e = hipLaunchCooperativeKernel(
                    (void*)lstm_persist, dim3(256), dim3(1024), args, 0, stream);
                if (e != hipSuccess) { (void)hipGetLastError(); coop_ok = false; }
            }
            if (!coop_ok) {
                for (int trel = 0; trel < chunk; ++trel) {
                    int t = t0 + trel;
                    int rb = (t + 1) & 1, wb = t & 1;
                    const float* cp = (t == 0) ? c0 : cbuf;
                    lstm_step_mfma<<<dim3(256), dim3(256), 0, stream>>>(
                        whh_hi, whh_lo, gxp,
                        hpl + rb * 2 * BH, hpl + rb * 2 * BH + BH,
                        cp, cbuf,
                        hpl + wb * 2 * BH, hpl + wb * 2 * BH + BH,
                        out, t, trel);
                }
            }
        }
    } else {
        // small-ws fallback: fp32 gx GEMM + per-step MFMA recurrence
        ushort* whh_hi = (ushort*)(ws + 262144);
        ushort* whh_lo = whh_hi + 4194304;
        ushort* hpl    = whh_lo + 4194304;
        const size_t FIXED2 = 262144 + 2 * 8388608L + 524288;
        float* gxp = (float*)(ws + FIXED2);
        long Tc2 = ((long)ws_size - (long)FIXED2) / 1048576L;
        if (Tc2 > 512) Tc2 = 512;
        Tc2 &= ~1L;
        if (Tc2 < 2) Tc2 = 2;

        split_bf16<<<dim3(2048), dim3(256), 0, stream>>>(Whh, whh_hi, whh_lo, 4194304L);
        split_bf16<<<dim3(64),   dim3(256), 0, stream>>>(h0, hpl + 2 * BH, hpl + 3 * BH, (long)BH);

        for (int t0 = 0; t0 < 512; t0 += (int)Tc2) {
            int chunk = (512 - t0 < (int)Tc2) ? (512 - t0) : (int)Tc2;
            gx_gemm<<<dim3(32, chunk * 64 / BM), dim3(256), 0, stream>>>(
                x, Wih, bih, bhh, gxp, t0);
            for (int trel = 0; trel < chunk; ++trel) {
                int t = t0 + trel;
                int rb = (t + 1) & 1, wb = t & 1;
                const float* cp = (t == 0) ? c0 : cbuf;
                lstm_step_mfma<<<dim3(256), dim3(256), 0, stream>>>(
                    whh_hi, whh_lo, gxp,
                    hpl + rb * 2 * BH, hpl + rb * 2 * BH + BH,
                    cp, cbuf,
                    hpl + wb * 2 * BH, hpl + wb * 2 * BH + BH,
                    out, t, trel);
            }
        }
    }
}